// Round 5
// baseline (376.768 us; speedup 1.0000x reference)
//
#include <hip/hip_runtime.h>
#include <hip/hip_bf16.h>

// B=4, S=2048, D_MODEL=1024, H=16, HEAD=64. Inputs fp32, output fp32.
#define S_LEN 2048
#define DM    1024
#define NH    16
#define HD    64

typedef __attribute__((ext_vector_type(8))) short short8;   // 8 bf16 (MFMA A/B frag)
typedef __attribute__((ext_vector_type(4))) short short4v;  // 4 bf16 (8B store)
typedef __attribute__((ext_vector_type(4))) float f32x4;    // MFMA C/D frag

// fp32 -> bf16 RNE (weight/output paths)
__device__ __forceinline__ short f2bf(float f) {
    union { float f; unsigned u; } x; x.f = f;
    unsigned u = x.u;
    return (short)((u + 0x7FFFu + ((u >> 16) & 1u)) >> 16);
}
// round-half-up variants (2 VALU; bias negligible for continuous data)
__device__ __forceinline__ short f2bf_ru(float f) {
    return (short)((__float_as_uint(f) + 0x8000u) >> 16);
}
__device__ __forceinline__ unsigned pk2bf(float a, float b) {
    unsigned ua = __float_as_uint(a) + 0x8000u;
    unsigned ub = __float_as_uint(b) + 0x8000u;
    return (ua >> 16) | (ub & 0xFFFF0000u);
}
__device__ __forceinline__ float fexp2(float x) {
#if __has_builtin(__builtin_amdgcn_exp2f)
    return __builtin_amdgcn_exp2f(x);
#else
    return exp2f(x);
#endif
}
// async global->LDS, 16B per lane (wave-uniform base + lane*16 dest)
__device__ __forceinline__ void gload_lds16(const void* g, void* l) {
    __builtin_amdgcn_global_load_lds(
        (const __attribute__((address_space(1))) unsigned int*)g,
        (__attribute__((address_space(3))) unsigned int*)l, 16, 0, 0);
}

// ---------------------------------------------------------------------------
// Kernel 1: W [K][N] fp32 -> WT [N][K] bf16 for Wq/Wk/Wv (blockIdx.z)
// ---------------------------------------------------------------------------
__global__ void wt_kernel(const float* __restrict__ Wq, const float* __restrict__ Wk,
                          const float* __restrict__ Wv, short* __restrict__ wt_base) {
    __shared__ float t[32][33];
    const float* W = (blockIdx.z == 0) ? Wq : (blockIdx.z == 1 ? Wk : Wv);
    short* WT = wt_base + (size_t)blockIdx.z * DM * DM;
    int kb = blockIdx.x * 32, nb = blockIdx.y * 32;
    int tx = threadIdx.x, ty = threadIdx.y;  // 32 x 8
#pragma unroll
    for (int r = 0; r < 4; r++)
        t[ty + 8 * r][tx] = W[(size_t)(kb + ty + 8 * r) * DM + nb + tx];
    __syncthreads();
#pragma unroll
    for (int r = 0; r < 4; r++)
        WT[(size_t)(nb + ty + 8 * r) * DM + kb + tx] = f2bf(t[tx][ty + 8 * r]);
}

// ---------------------------------------------------------------------------
// Kernel 2: bulk fp32 -> bf16 for the three X inputs (z selects input/dest).
// ---------------------------------------------------------------------------
__global__ __launch_bounds__(256) void cvt_kernel(
        const float* __restrict__ Xq, const float* __restrict__ Xk,
        const float* __restrict__ Xv, short* __restrict__ Yq,
        short* __restrict__ Yk, short* __restrict__ Yv) {
    const int z = blockIdx.z;
    const float* X = (z == 0) ? Xq : (z == 1) ? Xk : Xv;
    short* Y = (z == 0) ? Yq : (z == 1) ? Yk : Yv;
    size_t i = ((size_t)blockIdx.x * 256 + threadIdx.x) * 8;
    float4 a = *(const float4*)(X + i);
    float4 b = *(const float4*)(X + i + 4);
    uint2 p0, p1;
    p0.x = pk2bf(a.x, a.y); p0.y = pk2bf(a.z, a.w);
    p1.x = pk2bf(b.x, b.y); p1.y = pk2bf(b.z, b.w);
    *(uint2*)(Y + i) = p0;
    *(uint2*)(Y + i + 4) = p1;
}

// ---------------------------------------------------------------------------
// Kernel 3 (primary): pure-bf16 projection GEMM, m97 staging for BOTH operands.
// Tile 128x128, BK=32, LDS dbuf, ONE barrier/iter, next tile staged right
// after the barrier (drained ~a full body later). z = 0:Q, 1:K, 2:V.
// z<2: out head-major [b][h][s][64].  z==2: out transposed [b][h][64][S].
// ---------------------------------------------------------------------------
__global__ __launch_bounds__(256, 4) void projc_kernel(
        const short* __restrict__ Xq, const short* __restrict__ Xk,
        const short* __restrict__ Xv, const short* __restrict__ WT3,
        const float* __restrict__ bq, const float* __restrict__ bk,
        const float* __restrict__ bv,
        short* __restrict__ Qh, short* __restrict__ Kh, short* __restrict__ Vt,
        float qscale) {
    __shared__ __align__(16) short As[2][128 * 32];
    __shared__ __align__(16) short Bs[2][128 * 32];
    const int z = blockIdx.z;
    const short* X = (z == 0) ? Xq : (z == 1) ? Xk : Xv;
    const short* WT = WT3 + (size_t)z * DM * DM;
    const float* bias = (z == 0) ? bq : (z == 1) ? bk : bv;
    short* out = (z == 0) ? Qh : (z == 1) ? Kh : Vt;
    const float scale = (z == 0) ? qscale : 1.0f;
    const int mode = (z == 2);

    const int tid = threadIdx.x;
    const int lane = tid & 63, w = tid >> 6;
    const int l15 = lane & 15, quad = lane >> 4;
    const int n0 = blockIdx.x * 128, m0 = blockIdx.y * 128;
    const int wm = (w & 1) * 64, wn = (w >> 1) * 64;

    f32x4 acc[4][4];
#pragma unroll
    for (int i = 0; i < 4; i++)
#pragma unroll
        for (int j = 0; j < 4; j++) { acc[i][j][0] = 0.f; acc[i][j][1] = 0.f; acc[i][j][2] = 0.f; acc[i][j][3] = 0.f; }

    const int srow = tid >> 2, sko = (tid & 3) * 8;   // staging: 4 lanes/row, 16B each
    auto stage = [&](int k0, int bi) {
#pragma unroll
        for (int it = 0; it < 2; it++) {
            int row = it * 64 + srow;
            gload_lds16(X  + (size_t)(m0 + row) * DM + k0 + sko, As[bi] + row * 32 + sko);
            gload_lds16(WT + (size_t)(n0 + row) * DM + k0 + sko, Bs[bi] + row * 32 + sko);
        }
    };

    stage(0, 0);
    for (int t = 0; t < 32; t++) {
        const int bi = t & 1;
        __syncthreads();                      // tile t resident; buf^1 free
        if (t < 31) stage((t + 1) * 32, bi ^ 1);

        short8 af[4], bf[4];
#pragma unroll
        for (int i = 0; i < 4; i++)
            af[i] = *(const short8*)(As[bi] + (wm + i * 16 + l15) * 32 + quad * 8);
#pragma unroll
        for (int j = 0; j < 4; j++)
            bf[j] = *(const short8*)(Bs[bi] + (wn + j * 16 + l15) * 32 + quad * 8);
#pragma unroll
        for (int i = 0; i < 4; i++)
#pragma unroll
            for (int j = 0; j < 4; j++)
                acc[i][j] = __builtin_amdgcn_mfma_f32_16x16x32_bf16(af[i], bf[j], acc[i][j], 0, 0, 0);
    }

#pragma unroll
    for (int j = 0; j < 4; j++) {
        int col = n0 + wn + j * 16 + l15;
        float bv_ = bias[col];
        int h = col >> 6, d = col & 63;
#pragma unroll
        for (int i = 0; i < 4; i++) {
            int rowbase = m0 + wm + i * 16 + quad * 4;
            int bb = rowbase >> 11, s0 = rowbase & 2047;
            if (mode == 0) {
#pragma unroll
                for (int r = 0; r < 4; r++)
                    out[((size_t)(bb * NH + h) * S_LEN + (s0 + r)) * HD + d] =
                        f2bf((acc[i][j][r] + bv_) * scale);
            } else {
                short4v pk;
#pragma unroll
                for (int r = 0; r < 4; r++) pk[r] = f2bf((acc[i][j][r] + bv_) * scale);
                *(short4v*)(out + ((size_t)(bb * NH + h) * HD + d) * S_LEN + s0) = pk;
            }
        }
    }
}

// ---------------------------------------------------------------------------
// Kernel 3b (fallback if ws too small): R4's inline-convert projection.
// ---------------------------------------------------------------------------
__global__ __launch_bounds__(256, 3) void projf_kernel(
        const float* __restrict__ Xq, const float* __restrict__ Xk,
        const float* __restrict__ Xv, const short* __restrict__ WT3,
        const float* __restrict__ bq, const float* __restrict__ bk,
        const float* __restrict__ bv,
        short* __restrict__ Qh, short* __restrict__ Kh, short* __restrict__ Vt,
        float qscale) {
    __shared__ __align__(16) short As[2][128 * 32];
    __shared__ __align__(16) short Bs[2][128 * 32];
    const int z = blockIdx.z;
    const float* X = (z == 0) ? Xq : (z == 1) ? Xk : Xv;
    const short* WT = WT3 + (size_t)z * DM * DM;
    const float* bias = (z == 0) ? bq : (z == 1) ? bk : bv;
    short* out = (z == 0) ? Qh : (z == 1) ? Kh : Vt;
    const float scale = (z == 0) ? qscale : 1.0f;
    const int mode = (z == 2);

    const int tid = threadIdx.x;
    const int lane = tid & 63, w = tid >> 6;
    const int l15 = lane & 15, quad = lane >> 4;
    const int n0 = blockIdx.x * 128, m0 = blockIdx.y * 128;
    const int wm = (w & 1) * 64, wn = (w >> 1) * 64;
    const int arow = tid >> 3;
    const int ako  = (tid & 7) * 4;
    const float* xb = X + (size_t)m0 * DM;

    f32x4 acc[4][4];
#pragma unroll
    for (int i = 0; i < 4; i++)
#pragma unroll
        for (int j = 0; j < 4; j++) { acc[i][j][0] = 0.f; acc[i][j][1] = 0.f; acc[i][j][2] = 0.f; acc[i][j][3] = 0.f; }

    float4 araw[4];
#pragma unroll
    for (int it = 0; it < 4; it++)
        araw[it] = *(const float4*)(xb + (size_t)(it * 32 + arow) * DM + ako);
#pragma unroll
    for (int it = 0; it < 2; it++) {
        int c = it * 256 + tid;
        int row = c >> 2, ko = (c & 3) * 8;
        gload_lds16(WT + (size_t)(n0 + row) * DM + ko, Bs[0] + c * 8);
    }
#pragma unroll
    for (int it = 0; it < 4; it++) {
        int row = it * 32 + arow;
        uint2 p; p.x = pk2bf(araw[it].x, araw[it].y); p.y = pk2bf(araw[it].z, araw[it].w);
        *(uint2*)(As[0] + row * 32 + ako) = p;
    }

    for (int t = 0; t < 32; t++) {
        const int bi = t & 1;
        const int kn = t * 32 + 32;
        __syncthreads();

        short8 af[4], bf[4];
#pragma unroll
        for (int i = 0; i < 4; i++)
            af[i] = *(const short8*)(As[bi] + (wm + i * 16 + l15) * 32 + quad * 8);
#pragma unroll
        for (int j = 0; j < 4; j++)
            bf[j] = *(const short8*)(Bs[bi] + (wn + j * 16 + l15) * 32 + quad * 8);

        if (t < 31) {
#pragma unroll
            for (int it = 0; it < 4; it++)
                araw[it] = *(const float4*)(xb + (size_t)(it * 32 + arow) * DM + kn + ako);
#pragma unroll
            for (int it = 0; it < 2; it++) {
                int c = it * 256 + tid;
                int row = c >> 2, ko = (c & 3) * 8;
                gload_lds16(WT + (size_t)(n0 + row) * DM + kn + ko, Bs[bi ^ 1] + c * 8);
            }
        }

#pragma unroll
        for (int i = 0; i < 4; i++)
#pragma unroll
            for (int j = 0; j < 4; j++)
                acc[i][j] = __builtin_amdgcn_mfma_f32_16x16x32_bf16(af[i], bf[j], acc[i][j], 0, 0, 0);

        if (t < 31) {
#pragma unroll
            for (int it = 0; it < 4; it++) {
                int row = it * 32 + arow;
                uint2 p; p.x = pk2bf(araw[it].x, araw[it].y); p.y = pk2bf(araw[it].z, araw[it].w);
                *(uint2*)(As[bi ^ 1] + row * 32 + ako) = p;
            }
        }
    }

#pragma unroll
    for (int j = 0; j < 4; j++) {
        int col = n0 + wn + j * 16 + l15;
        float bv_ = bias[col];
        int h = col >> 6, d = col & 63;
#pragma unroll
        for (int i = 0; i < 4; i++) {
            int rowbase = m0 + wm + i * 16 + quad * 4;
            int bb = rowbase >> 11, s0 = rowbase & 2047;
            if (mode == 0) {
#pragma unroll
                for (int r = 0; r < 4; r++)
                    out[((size_t)(bb * NH + h) * S_LEN + (s0 + r)) * HD + d] =
                        f2bf((acc[i][j][r] + bv_) * scale);
            } else {
                short4v pk;
#pragma unroll
                for (int r = 0; r < 4; r++) pk[r] = f2bf((acc[i][j][r] + bv_) * scale);
                *(short4v*)(out + ((size_t)(bb * NH + h) * HD + d) * S_LEN + s0) = pk;
            }
        }
    }
}

// ---------------------------------------------------------------------------
// Kernel 4: attention. 256 thr (4 waves), q-tile 128 (wave: 2x16-row strips).
// K staged block-cooperatively (dbuf LDS, 1 barrier/iter, staged right after
// the barrier). V read per-wave direct from global (Vt: [b][h][64][S]) in two
// halves: first issued before exp (latency hides under exp+P-store+lgkm wait),
// second after P-stores. LDS = 16K (K dbuf) + 18.4K (P) = 34.8 KB -> 4 blk/CU.
// No-max softmax (Q pre-scaled by 0.125*log2e, exp2); P via wave-private LDS.
// ---------------------------------------------------------------------------
__global__ __launch_bounds__(256, 4) void attn_kernel(
        const short* __restrict__ Q, const short* __restrict__ K,
        const short* __restrict__ V, float* __restrict__ out) {
    __shared__ __align__(16) short Ks[2][2][64][32];  // [buf][half][key-row][32] 16KB
    __shared__ __align__(16) short ps[4][2][16 * 72]; // [wave][strip]          18.4KB
    const int tid = threadIdx.x;
    const int lane = tid & 63, w = tid >> 6;
    const int l15 = lane & 15, quad = lane >> 4;
    const int b = blockIdx.z, h = blockIdx.y;
    const int q0 = blockIdx.x * 128;
    const size_t bh = (size_t)(b * NH + h);
    const short* qp = Q + bh * S_LEN * HD;
    const short* kp = K + bh * S_LEN * HD;
    const short* vp = V + bh * (size_t)HD * S_LEN;

    short8 qa[2][2];
#pragma unroll
    for (int s = 0; s < 2; s++) {
        const short* qr = qp + (size_t)(q0 + w * 32 + s * 16 + l15) * HD + quad * 8;
        qa[s][0] = *(const short8*)(qr);
        qa[s][1] = *(const short8*)(qr + 32);
    }

    f32x4 o[2][4];
    float lsum[2][4];
#pragma unroll
    for (int s = 0; s < 2; s++)
#pragma unroll
        for (int d = 0; d < 4; d++) {
            o[s][d][0] = 0.f; o[s][d][1] = 0.f; o[s][d][2] = 0.f; o[s][d][3] = 0.f;
            lsum[s][d] = 0.f;
        }

    auto stageK = [&](int kt, int bi) {
        short* kd = &Ks[bi][0][0][0];
#pragma unroll
        for (int it = 0; it < 2; it++) {
            int c = it * 256 + tid;                  // 512 slots x 16B = 8KB
            int half = c >> 8, row = (c >> 2) & 63, chunk = c & 3;
            gload_lds16(kp + (size_t)(kt + row) * HD + half * 32 + chunk * 8, kd + c * 8);
        }
    };

    stageK(0, 0);

    for (int t = 0; t < 32; t++) {
        const int bi = t & 1;
        const int kt = t << 6;
        __syncthreads();                 // K tile t resident; buf^1 free
        if (t < 31) stageK(kt + 64, bi ^ 1);

        // ---- QK^T: K frags from LDS, 2 strips x 16x64 ----
        f32x4 sacc[2][4];
#pragma unroll
        for (int nb = 0; nb < 4; nb++) {
            short8 k0v = *(const short8*)(&Ks[bi][0][nb * 16 + l15][quad * 8]);
            short8 k1v = *(const short8*)(&Ks[bi][1][nb * 16 + l15][quad * 8]);
#pragma unroll
            for (int s = 0; s < 2; s++) {
                f32x4 zz; zz[0] = 0.f; zz[1] = 0.f; zz[2] = 0.f; zz[3] = 0.f;
                zz = __builtin_amdgcn_mfma_f32_16x16x32_bf16(qa[s][0], k0v, zz, 0, 0, 0);
                sacc[s][nb] = __builtin_amdgcn_mfma_f32_16x16x32_bf16(qa[s][1], k1v, zz, 0, 0, 0);
            }
        }

        // ---- issue V first half (d 0..31) before the exp chain ----
        short8 vf0[4];
#pragma unroll
        for (int dd = 0; dd < 2; dd++) {
            const short* vr = vp + (size_t)(dd * 16 + l15) * S_LEN + kt + quad * 8;
            vf0[2 * dd]     = *(const short8*)(vr);
            vf0[2 * dd + 1] = *(const short8*)(vr + 32);
        }

        // ---- P = exp2(S'); partial row-sums; P -> wave-private LDS ----
#pragma unroll
        for (int s = 0; s < 2; s++)
#pragma unroll
            for (int r = 0; r < 4; r++)
#pragma unroll
                for (int nb = 0; nb < 4; nb++) {
                    float p = fexp2(sacc[s][nb][r]);
                    lsum[s][r] += p;
                    ps[w][s][(quad * 4 + r) * 72 + nb * 16 + l15] = f2bf_ru(p);
                }

        // ---- issue V second half (d 32..63) ----
        short8 vf1[4];
#pragma unroll
        for (int dd = 0; dd < 2; dd++) {
            const short* vr = vp + (size_t)((dd + 2) * 16 + l15) * S_LEN + kt + quad * 8;
            vf1[2 * dd]     = *(const short8*)(vr);
            vf1[2 * dd + 1] = *(const short8*)(vr + 32);
        }

        asm volatile("s_waitcnt lgkmcnt(0)" ::: "memory");
        short8 pa[2][2];
#pragma unroll
        for (int s = 0; s < 2; s++) {
            pa[s][0] = *(const short8*)(&ps[w][s][l15 * 72 + quad * 8]);
            pa[s][1] = *(const short8*)(&ps[w][s][l15 * 72 + 32 + quad * 8]);
        }

        // ---- O += P V ----
#pragma unroll
        for (int dd = 0; dd < 2; dd++)
#pragma unroll
            for (int s = 0; s < 2; s++) {
                o[s][dd] = __builtin_amdgcn_mfma_f32_16x16x32_bf16(pa[s][0], vf0[2 * dd], o[s][dd], 0, 0, 0);
                o[s][dd] = __builtin_amdgcn_mfma_f32_16x16x32_bf16(pa[s][1], vf0[2 * dd + 1], o[s][dd], 0, 0, 0);
            }
#pragma unroll
        for (int dd = 0; dd < 2; dd++)
#pragma unroll
            for (int s = 0; s < 2; s++) {
                o[s][dd + 2] = __builtin_amdgcn_mfma_f32_16x16x32_bf16(pa[s][0], vf1[2 * dd], o[s][dd + 2], 0, 0, 0);
                o[s][dd + 2] = __builtin_amdgcn_mfma_f32_16x16x32_bf16(pa[s][1], vf1[2 * dd + 1], o[s][dd + 2], 0, 0, 0);
            }
    }

    // ---- deferred l reduction + epilogue ----
#pragma unroll
    for (int s = 0; s < 2; s++) {
#pragma unroll
        for (int r = 0; r < 4; r++) {
            float l = lsum[s][r];
            l += __shfl_xor(l, 1);
            l += __shfl_xor(l, 2);
            l += __shfl_xor(l, 4);
            l += __shfl_xor(l, 8);
            lsum[s][r] = 1.f / l;
        }
        float* orow = out + ((size_t)b * S_LEN + q0 + w * 32 + s * 16 + quad * 4) * DM + h * HD + l15;
#pragma unroll
        for (int r = 0; r < 4; r++)
#pragma unroll
            for (int dd = 0; dd < 4; dd++)
                orow[(size_t)r * DM + dd * 16] = o[s][dd][r] * lsum[s][r];
    }
}

// ---------------------------------------------------------------------------
// ws layout (shorts): WT[0, 3.1M) | Qh | Kh | Vt (8.39M each) | Xv (8.39M)
// Primary path needs ws >= 73,400,320 B; Xq/Xk bf16 live in d_out (2x16.8MB).
// ---------------------------------------------------------------------------
extern "C" void kernel_launch(void* const* d_in, const int* in_sizes, int n_in,
                              void* d_out, int out_size, void* d_ws, size_t ws_size,
                              hipStream_t stream) {
    const float* query  = (const float*)d_in[0];
    const float* key_in = (const float*)d_in[1];
    const float* value  = (const float*)d_in[2];
    const float* Wq = (const float*)d_in[3];
    const float* bq = (const float*)d_in[4];
    const float* Wk = (const float*)d_in[5];
    const float* bk = (const float*)d_in[6];
    const float* Wv = (const float*)d_in[7];
    const float* bv = (const float*)d_in[8];

    short* wt = (short*)d_ws;
    short* Qh = wt + 3 * 1048576;
    short* Kh = Qh + 8388608;
    short* Vt = Kh + 8388608;
    short* Xv = Vt + 8388608;           // only used on the primary path
    float* out = (float*)d_out;

    const float QSCALE = 0.125f * 1.44269504088896340736f;  // 1/sqrt(64) * log2(e)

    wt_kernel<<<dim3(32, 32, 3), dim3(32, 8), 0, stream>>>(Wq, Wk, Wv, wt);

    if (ws_size >= 73400320u) {
        short* Xq = (short*)d_out;              // 16.8 MB
        short* Xk = Xq + 8388608;               // 16.8 MB (d_out = 33.5 MB total)
        cvt_kernel<<<dim3(4096, 1, 3), 256, 0, stream>>>(query, key_in, value, Xq, Xk, Xv);
        projc_kernel<<<dim3(8, 64, 3), 256, 0, stream>>>(Xq, Xk, Xv, wt,
                                                         bq, bk, bv, Qh, Kh, Vt, QSCALE);
    } else {
        projf_kernel<<<dim3(8, 64, 3), 256, 0, stream>>>(query, key_in, value, wt,
                                                         bq, bk, bv, Qh, Kh, Vt, QSCALE);
    }

    attn_kernel<<<dim3(16, NH, 4), 256, 0, stream>>>(Qh, Kh, Vt, out);
}